// Round 8
// baseline (113.049 us; speedup 1.0000x reference)
//
#include <hip/hip_runtime.h>
#include <math.h>

#define NROWS 32768
#define DDIM  1024
#define NEXP  64
#define TAU   2e-4f
#define EPSF  1e-9f
#define CAPMAX 8192
#define NSHARD 8

typedef __attribute__((ext_vector_type(8)))  short  short8;
typedef __attribute__((ext_vector_type(16))) float  f32x16;

// stable greater-than: value desc, index asc on ties (matches lax.top_k)
__device__ __forceinline__ bool gt_(float a, int ea, float b, int eb)
{ return a > b || (a == b && ea < eb); }

// split f into bf16 hi (RN) + bf16 lo (RN of residual)
__device__ __forceinline__ void cvt_hl(float f, unsigned short& h, unsigned short& l)
{
    unsigned u  = __float_as_uint(f);
    unsigned hu = (u + 0x7FFFu + ((u >> 16) & 1u)) & 0xFFFF0000u;
    h = (unsigned short)(hu >> 16);
    float r = f - __uint_as_float(hu);
    unsigned v = __float_as_uint(r);
    l = (unsigned short)((v + 0x7FFFu + ((v >> 16) & 1u)) >> 16);
}

// ---------------------------------------------------------------------------
// Pack gate_w ONCE into per-lane MFMA B-fragment order, bf16 hi+lo
// (fragment lane-mapping HW-verified R5-R7). Block 0 zeroes aux shards + cnt.
// ---------------------------------------------------------------------------
__global__ void wpack_kernel(const float* __restrict__ gw,
                             unsigned short* __restrict__ wp,
                             float* __restrict__ shard,
                             int* __restrict__ cnt)
{
    if (blockIdx.x == 0) {
        shard[threadIdx.x]       = 0.0f;
        shard[256 + threadIdx.x] = 0.0f;
        if (threadIdx.x == 0) *cnt = 0;
    }
    const int kc = blockIdx.x;              // 0..63
    const int t  = threadIdx.x;             // 256
    const int lane = t & 63, g = (t >> 6) & 1, pr = t >> 7;
    const int e = g * 32 + (lane & 31);
    const int k = kc * 16 + (lane >> 5) * 8;
    float4 f0 = *reinterpret_cast<const float4*>(gw + (size_t)e * DDIM + k);
    float4 f1 = *reinterpret_cast<const float4*>(gw + (size_t)e * DDIM + k + 4);
    float f[8] = {f0.x, f0.y, f0.z, f0.w, f1.x, f1.y, f1.z, f1.w};
    short8 o;
    #pragma unroll
    for (int j = 0; j < 8; ++j) {
        unsigned short hh, ll;
        cvt_hl(f[j], hh, ll);
        o[j] = pr ? (short)ll : (short)hh;
    }
    *reinterpret_cast<short8*>(wp + ((size_t)((kc * 2 + g) * 2 + pr) * 64 + lane) * 8) = o;
}

// ---------------------------------------------------------------------------
// Main: barrier-free streaming GEMM (R6 structure, verified). grid 1024 x
// 256 thr; block = 32 rows, wave = one K-quarter (16 kc of 16 fp32 k).
// Per kc: load x-frag straight from global (2 float4/lane, L1/L3-amplified
// gather but never drained), convert to bf16 hi/lo in-register, load 4
// pre-packed B-frags (coalesced short8, L2-resident), 6 MFMAs (xl*wl term
// dropped, ~3e-7 on logits). One-kc register prefetch; NO barriers until
// the end-of-kernel 4-way split-K LDS tree. Aux via 8-sharded atomics (R7).
// ---------------------------------------------------------------------------
__global__ __launch_bounds__(256, 3) void moe_main(
    const float* __restrict__ x, const unsigned short* __restrict__ wp,
    float* __restrict__ out, float* __restrict__ shard,
    int* __restrict__ cnt, int* __restrict__ list, int cap)
{
    __shared__ float red[2][16][2][64];     // 16 KB reduce regions

    const int t = threadIdx.x;
    const int wave = t >> 6, lane = t & 63;
    const int l31 = lane & 31, l5 = lane >> 5;
    const int row0 = blockIdx.x * 32;

    f32x16 acc0, acc1;
    #pragma unroll
    for (int r = 0; r < 16; ++r) { acc0[r] = 0.0f; acc1[r] = 0.0f; }

    const float* xq = x + (size_t)(row0 + l31) * DDIM + l5 * 8 + wave * 256;
    const unsigned short* wq = wp + (size_t)lane * 8 + (size_t)wave * 32768;

    float4 xa[2], xb[2];
    short8 bh0[2], bl0[2], bh1[2], bl1[2];

    xa[0]  = *reinterpret_cast<const float4*>(xq);
    xb[0]  = *reinterpret_cast<const float4*>(xq + 4);
    bh0[0] = *reinterpret_cast<const short8*>(wq);
    bl0[0] = *reinterpret_cast<const short8*>(wq + 512);
    bh1[0] = *reinterpret_cast<const short8*>(wq + 1024);
    bl1[0] = *reinterpret_cast<const short8*>(wq + 1536);

    #pragma unroll
    for (int i = 0; i < 16; ++i) {
        const int cur = i & 1, nxt = cur ^ 1;
        if (i < 15) {                       // prefetch next kc
            const int xo = (i + 1) * 16;
            const int wo = (i + 1) * 2048;
            xa[nxt]  = *reinterpret_cast<const float4*>(xq + xo);
            xb[nxt]  = *reinterpret_cast<const float4*>(xq + xo + 4);
            bh0[nxt] = *reinterpret_cast<const short8*>(wq + wo);
            bl0[nxt] = *reinterpret_cast<const short8*>(wq + wo + 512);
            bh1[nxt] = *reinterpret_cast<const short8*>(wq + wo + 1024);
            bl1[nxt] = *reinterpret_cast<const short8*>(wq + wo + 1536);
        }
        float f[8] = {xa[cur].x, xa[cur].y, xa[cur].z, xa[cur].w,
                      xb[cur].x, xb[cur].y, xb[cur].z, xb[cur].w};
        short8 ah, al;
        #pragma unroll
        for (int j = 0; j < 8; ++j) {
            unsigned short hh, ll;
            cvt_hl(f[j], hh, ll);
            ah[j] = (short)hh; al[j] = (short)ll;
        }
        acc0 = __builtin_amdgcn_mfma_f32_32x32x16_bf16(ah, bh0[cur], acc0, 0, 0, 0);
        acc1 = __builtin_amdgcn_mfma_f32_32x32x16_bf16(ah, bh1[cur], acc1, 0, 0, 0);
        acc0 = __builtin_amdgcn_mfma_f32_32x32x16_bf16(al, bh0[cur], acc0, 0, 0, 0);
        acc1 = __builtin_amdgcn_mfma_f32_32x32x16_bf16(al, bh1[cur], acc1, 0, 0, 0);
        acc0 = __builtin_amdgcn_mfma_f32_32x32x16_bf16(ah, bl0[cur], acc0, 0, 0, 0);
        acc1 = __builtin_amdgcn_mfma_f32_32x32x16_bf16(ah, bl1[cur], acc1, 0, 0, 0);
    }

    // ---- 4-way split-K reduction (tree through LDS) -----------------------
    __syncthreads();
    if (wave >= 2) {
        #pragma unroll
        for (int r = 0; r < 16; ++r) {
            red[wave - 2][r][0][lane] = acc0[r];
            red[wave - 2][r][1][lane] = acc1[r];
        }
    }
    __syncthreads();
    if (wave < 2) {
        #pragma unroll
        for (int r = 0; r < 16; ++r) {
            acc0[r] += red[wave][r][0][lane];
            acc1[r] += red[wave][r][1][lane];
        }
    }
    __syncthreads();
    if (wave == 1) {
        #pragma unroll
        for (int r = 0; r < 16; ++r) {
            red[0][r][0][lane] = acc0[r];
            red[0][r][1][lane] = acc1[r];
        }
    }
    __syncthreads();
    if (wave != 0) return;                  // all barriers complete
    #pragma unroll
    for (int r = 0; r < 16; ++r) {
        acc0[r] += red[0][r][0][lane];
        acc1[r] += red[0][r][1][lane];
    }

    // ---- epilogue (wave 0 only; verified R6/R7) ---------------------------
    float* lgs = &red[0][0][0][0];          // reuse as [32][72] f32
    #pragma unroll
    for (int r = 0; r < 16; ++r) {          // C layout: col=lane&31, row=(r&3)+8*(r>>2)+4*l5
        const int row = (r & 3) + 8 * (r >> 2) + 4 * l5;
        lgs[row * 72 + l31]      = acc0[r];
        lgs[row * 72 + 32 + l31] = acc1[r];
    }
    const int rr = lane >> 1, h = lane & 1;
    float L[32];
    #pragma unroll
    for (int i = 0; i < 8; ++i) {
        float4 v = *reinterpret_cast<const float4*>(lgs + rr * 72 + h * 32 + i * 4);
        L[4*i] = v.x; L[4*i+1] = v.y; L[4*i+2] = v.z; L[4*i+3] = v.w;
    }
    float v1 = -3.4e38f, v2 = -3.4e38f, v3 = -3.4e38f;
    int   e1 = 1 << 30,  e2 = 1 << 30,  e3 = 1 << 30;
    #pragma unroll
    for (int i = 0; i < 32; ++i) {
        float v = L[i]; int e = h * 32 + i;
        if      (gt_(v, e, v1, e1)) { v3=v2; e3=e2; v2=v1; e2=e1; v1=v; e1=e; }
        else if (gt_(v, e, v2, e2)) { v3=v2; e3=e2; v2=v; e2=e; }
        else if (gt_(v, e, v3, e3)) { v3=v; e3=e; }
    }
    {   // merge the row's two lanes (xor 1), stable 3-way
        float o1 = __shfl_xor(v1, 1), o2 = __shfl_xor(v2, 1), o3 = __shfl_xor(v3, 1);
        int  oe1 = __shfl_xor(e1, 1), oe2 = __shfl_xor(e2, 1), oe3 = __shfl_xor(e3, 1);
        float n1, n2, n3; int m1, m2, m3;
        if (gt_(v1, e1, o1, oe1)) {
            n1 = v1; m1 = e1;
            if (gt_(v2, e2, o1, oe1)) {
                n2 = v2; m2 = e2;
                if (gt_(v3, e3, o1, oe1)) { n3 = v3; m3 = e3; } else { n3 = o1; m3 = oe1; }
            } else {
                n2 = o1; m2 = oe1;
                if (gt_(v2, e2, o2, oe2)) { n3 = v2; m3 = e2; } else { n3 = o2; m3 = oe2; }
            }
        } else {
            n1 = o1; m1 = oe1;
            if (gt_(o2, oe2, v1, e1)) {
                n2 = o2; m2 = oe2;
                if (gt_(o3, oe3, v1, e1)) { n3 = o3; m3 = oe3; } else { n3 = v1; m3 = e1; }
            } else {
                n2 = v1; m2 = e1;
                if (gt_(o2, oe2, v2, e2)) { n3 = o2; m3 = oe2; } else { n3 = v2; m3 = e2; }
            }
        }
        v1 = n1; e1 = m1; v2 = n2; e2 = m2; v3 = n3; e3 = m3;
    }
    float S = 0.0f;
    #pragma unroll
    for (int i = 0; i < 32; ++i) { L[i] = expf(L[i] - v1); S += L[i]; }
    S += __shfl_xor(S, 1);
    const float invS = 1.0f / S;
    #pragma unroll
    for (int i = 0; i < 32; ++i) L[i] *= invS;
    // cross-row butterfly (bit0 = h preserved): lanes 0/1 hold expert sums
    #pragma unroll
    for (int m = 2; m <= 32; m <<= 1)
        #pragma unroll
        for (int i = 0; i < 32; ++i) L[i] += __shfl_xor(L[i], m);
    if (lane < 2) {
        float* sh = shard + (blockIdx.x & (NSHARD - 1)) * 64 + h * 32;
        #pragma unroll
        for (int i = 0; i < 32; ++i) atomicAdd(&sh[i], L[i]);
    }
    if (h == 0) {
        const float p1 = invS;                    // exp(v1-v1)*invS
        const float p2 = expf(v2 - v1) * invS;
        const float dn = p1 + p2 + EPSF;
        const int r = row0 + rr;
        out[2 * r]                 = p1 / dn;
        out[2 * r + 1]             = p2 / dn;
        out[2 * NROWS + 2 * r]     = (float)e1;
        out[2 * NROWS + 2 * r + 1] = (float)e2;
        if (cap > 0 && (v1 - v2 < TAU || v2 - v3 < TAU)) {
            int pos = atomicAdd(cnt, 1);
            if (pos < cap) list[pos] = r;
        }
    }
}

// ---------------------------------------------------------------------------
// Finalize: block 0 sums 8 aux shards -> aux loss; blocks 1..64 repair
// flagged rows with exact fp32 logits.
// ---------------------------------------------------------------------------
__global__ __launch_bounds__(256) void finalize_kernel(
    const float* __restrict__ x, const float* __restrict__ gw,
    float* __restrict__ out, const float* __restrict__ shard,
    const int* __restrict__ cnt, const int* __restrict__ list, int cap)
{
    if (blockIdx.x == 0) {
        const int tt = threadIdx.x;
        if (tt < 64) {
            float m = 0.0f;
            #pragma unroll
            for (int s = 0; s < NSHARD; ++s) m += shard[s * 64 + tt];
            m *= (1.0f / (float)NROWS);
            float v = m * logf(m + EPSF);
            #pragma unroll
            for (int k = 1; k <= 32; k <<= 1) v += __shfl_xor(v, k);
            if (tt == 0) out[4 * NROWS] = v;
        }
        return;
    }
    __shared__ float lg[64];
    const int n = (cap > 0) ? min(*cnt, cap) : 0;
    const int tt = threadIdx.x, e = tt >> 2, part = tt & 3;
    for (int j = (int)blockIdx.x - 1; j < n; j += 64) {
        const int row = list[j];
        const float* xr = x  + (size_t)row * DDIM + part * 256;
        const float* wr = gw + (size_t)e   * DDIM + part * 256;
        float a = 0.0f;
        #pragma unroll 8
        for (int kk = 0; kk < 64; ++kk) {
            float4 xv = *reinterpret_cast<const float4*>(xr + kk * 4);
            float4 wv = *reinterpret_cast<const float4*>(wr + kk * 4);
            a += xv.x * wv.x + xv.y * wv.y + xv.z * wv.z + xv.w * wv.w;
        }
        a += __shfl_xor(a, 1); a += __shfl_xor(a, 2);
        if (part == 0) lg[e] = a;
        __syncthreads();
        if (tt < 4) {
            const int q = tt;
            float v1 = -3.4e38f, v2 = -3.4e38f; int e1 = 1 << 30, e2 = 1 << 30;
            float Lr[16];
            #pragma unroll
            for (int i = 0; i < 16; ++i) {
                float v = Lr[i] = lg[q * 16 + i]; int ee = q * 16 + i;
                if      (gt_(v, ee, v1, e1)) { v2 = v1; e2 = e1; v1 = v; e1 = ee; }
                else if (gt_(v, ee, v2, e2)) { v2 = v; e2 = ee; }
            }
            #pragma unroll
            for (int m = 1; m <= 2; m <<= 1) {
                float o1 = __shfl_xor(v1, m), o2 = __shfl_xor(v2, m);
                int  oe1 = __shfl_xor(e1, m), oe2 = __shfl_xor(e2, m);
                float n1, n2; int m1, m2;
                if (gt_(v1, e1, o1, oe1)) {
                    n1 = v1; m1 = e1;
                    if (gt_(v2, e2, o1, oe1)) { n2 = v2; m2 = e2; } else { n2 = o1; m2 = oe1; }
                } else {
                    n1 = o1; m1 = oe1;
                    if (gt_(o2, oe2, v1, e1)) { n2 = o2; m2 = oe2; } else { n2 = v1; m2 = e1; }
                }
                v1 = n1; e1 = m1; v2 = n2; e2 = m2;
            }
            float s = 0.0f;
            #pragma unroll
            for (int i = 0; i < 16; ++i) s += expf(Lr[i] - v1);
            s += __shfl_xor(s, 1); s += __shfl_xor(s, 2);
            if (q == 0) {
                const float invS = 1.0f / s;
                const float p1 = invS, p2 = expf(v2 - v1) * invS;
                const float dn = p1 + p2 + EPSF;
                out[2 * row]                 = p1 / dn;
                out[2 * row + 1]             = p2 / dn;
                out[2 * NROWS + 2 * row]     = (float)e1;
                out[2 * NROWS + 2 * row + 1] = (float)e2;
            }
        }
        __syncthreads();
    }
}

extern "C" void kernel_launch(void* const* d_in, const int* in_sizes, int n_in,
                              void* d_out, int out_size, void* d_ws, size_t ws_size,
                              hipStream_t stream)
{
    const float* x  = (const float*)d_in[0];
    const float* gw = (const float*)d_in[1];
    float* out      = (float*)d_out;

    // d_ws layout: [wp 256KB][shard 2KB][cnt 4B pad->256B][list ...]
    unsigned short* wp = (unsigned short*)d_ws;
    float* shard   = (float*)((char*)d_ws + 262144);
    int*   cnt     = (int*)((char*)d_ws + 264192);
    int*   list    = (int*)((char*)d_ws + 264448);
    int cap = 0;
    if (ws_size >= 264448 + 4096) {
        size_t avail = (ws_size - 264448) / sizeof(int);
        cap = (avail > CAPMAX) ? CAPMAX : (int)avail;
    }

    hipLaunchKernelGGL(wpack_kernel, dim3(64), dim3(256), 0, stream,
                       gw, wp, shard, cnt);
    hipLaunchKernelGGL(moe_main, dim3(NROWS / 32), dim3(256), 0, stream,
                       x, wp, out, shard, cnt, list, cap);
    hipLaunchKernelGGL(finalize_kernel, dim3(65), dim3(256), 0, stream,
                       x, gw, out, shard, cnt, list, cap);
}

// Round 9
// 62.417 us; speedup vs baseline: 1.8112x; 1.8112x over previous
//
#include <hip/hip_runtime.h>
#include <math.h>

#define NROWS 32768
#define DDIM  1024
#define NEXP  64
#define TAU   2e-4f
#define EPSF  1e-9f
#define CAPMAX 8192
#define NSHARD 8

typedef __attribute__((ext_vector_type(8)))  short  short8;
typedef __attribute__((ext_vector_type(16))) float  f32x16;
typedef __attribute__((address_space(3))) unsigned int       lds_u32;
typedef __attribute__((address_space(1))) const unsigned int g_u32;

// stable greater-than: value desc, index asc on ties (matches lax.top_k)
__device__ __forceinline__ bool gt_(float a, int ea, float b, int eb)
{ return a > b || (a == b && ea < eb); }

// split f into bf16 hi (RN) + bf16 lo (RN of residual)
__device__ __forceinline__ void cvt_hl(float f, unsigned short& h, unsigned short& l)
{
    unsigned u  = __float_as_uint(f);
    unsigned hu = (u + 0x7FFFu + ((u >> 16) & 1u)) & 0xFFFF0000u;
    h = (unsigned short)(hu >> 16);
    float r = f - __uint_as_float(hu);
    unsigned v = __float_as_uint(r);
    l = (unsigned short)((v + 0x7FFFu + ((v >> 16) & 1u)) >> 16);
}

// ---------------------------------------------------------------------------
// Pack gate_w ONCE into per-lane MFMA B-fragment order, bf16 hi+lo
// (fragment lane-mapping HW-verified R5-R8). Block 0 zeroes aux shards + cnt.
// wp bytes: ((kc*2+g)*2+pr)*1024 + lane*16  (kc 0..63, g expert-half, pr hi/lo)
// ---------------------------------------------------------------------------
__global__ void wpack_kernel(const float* __restrict__ gw,
                             unsigned short* __restrict__ wp,
                             float* __restrict__ shard,
                             int* __restrict__ cnt)
{
    if (blockIdx.x == 0) {
        shard[threadIdx.x]       = 0.0f;
        shard[256 + threadIdx.x] = 0.0f;
        if (threadIdx.x == 0) *cnt = 0;
    }
    const int kc = blockIdx.x;              // 0..63
    const int t  = threadIdx.x;             // 256
    const int lane = t & 63, g = (t >> 6) & 1, pr = t >> 7;
    const int e = g * 32 + (lane & 31);
    const int k = kc * 16 + (lane >> 5) * 8;
    float4 f0 = *reinterpret_cast<const float4*>(gw + (size_t)e * DDIM + k);
    float4 f1 = *reinterpret_cast<const float4*>(gw + (size_t)e * DDIM + k + 4);
    float f[8] = {f0.x, f0.y, f0.z, f0.w, f1.x, f1.y, f1.z, f1.w};
    short8 o;
    #pragma unroll
    for (int j = 0; j < 8; ++j) {
        unsigned short hh, ll;
        cvt_hl(f[j], hh, ll);
        o[j] = pr ? (short)ll : (short)hh;
    }
    *reinterpret_cast<short8*>(wp + ((size_t)((kc * 2 + g) * 2 + pr) * 64 + lane) * 8) = o;
}

// ---------------------------------------------------------------------------
// Main: 2-buffer pipelined MFMA GEMM with COUNTED vmcnt (T3/T4 recipe).
// grid 512 x 256 thr; block = 64 rows x 64 experts; wave (wm,g) owns the
// 32x32 quadrant rows[wm*32..) x experts[g*32..) with FULL K (no split-K).
// Per chunk (BK=64 fp32 k = 4 kc):
//   issue 8 global_load_lds(16B) for chunk c+1  (x swizzled, B linear)
//   s_waitcnt vmcnt(8)   <- chunk c landed; c+1 stays IN FLIGHT
//   s_barrier; compute c (4 kc x {2 ds_read + cvt + 3 MFMA}); s_barrier
// x-tile XOR swizzle (rule 21): linear LDS dest + inverse-swizzled global
// source + swizzled ds_read,  byte ^= ((row&7)<<5).
// ---------------------------------------------------------------------------
__global__ __launch_bounds__(256, 2) void moe_main(
    const float* __restrict__ x, const unsigned short* __restrict__ wp,
    float* __restrict__ out, float* __restrict__ shard,
    int* __restrict__ cnt, int* __restrict__ list, int cap)
{
    extern __shared__ char smem[];          // 64 KB: x dbuf 2x16KB, B dbuf 2x16KB

    const int t = threadIdx.x;
    const int wave = t >> 6, lane = t & 63;
    const int wm = wave & 1, g = wave >> 1;
    const int l31 = lane & 31, l5 = lane >> 5;
    const int row0 = blockIdx.x * 64;
    const int arow = wm * 32 + l31;         // this lane's x row within tile

    f32x16 acc;
    #pragma unroll
    for (int r = 0; r < 16; ++r) acc[r] = 0.0f;

    #define STAGE(xb, bb, c_) do {                                               \
        const char* xs0_ = (const char*)x + (size_t)row0 * 4096 + (size_t)(c_) * 256; \
        const char* bs0_ = (const char*)wp + (size_t)(c_) * 16384;               \
        _Pragma("unroll")                                                        \
        for (int q_ = 0; q_ < 4; ++q_) {                                         \
            int d_ = q_ * 4096 + t * 16;                                         \
            int sw_ = d_ ^ (((d_ >> 8) & 7) << 5);                               \
            const char* xsrc_ = xs0_ + (size_t)(sw_ >> 8) * 4096 + (sw_ & 255);  \
            __builtin_amdgcn_global_load_lds((g_u32*)xsrc_,                      \
                (lds_u32*)(smem + (xb) + d_), 16, 0, 0);                         \
            __builtin_amdgcn_global_load_lds((g_u32*)(bs0_ + d_),                \
                (lds_u32*)(smem + (bb) + d_), 16, 0, 0);                         \
        }                                                                        \
    } while (0)

    STAGE(0, 32768, 0);                     // prologue: chunk 0

    for (int c = 0; c < 16; ++c) {
        const int xb = (c & 1) * 16384;
        const int bb = 32768 + (c & 1) * 16384;
        if (c < 15) {
            STAGE(((c + 1) & 1) * 16384, 32768 + ((c + 1) & 1) * 16384, c + 1);
            __builtin_amdgcn_sched_barrier(0);
            asm volatile("s_waitcnt vmcnt(8)" ::: "memory");
        } else {
            asm volatile("s_waitcnt vmcnt(0)" ::: "memory");
        }
        __builtin_amdgcn_s_barrier();
        __builtin_amdgcn_sched_barrier(0);

        #pragma unroll
        for (int j = 0; j < 4; ++j) {
            int lb = arow * 256 + j * 64 + l5 * 32;
            lb ^= ((arow & 7) << 5);
            const float* ap = reinterpret_cast<const float*>(smem + xb + lb);
            float4 f0 = *reinterpret_cast<const float4*>(ap);
            float4 f1 = *reinterpret_cast<const float4*>(ap + 4);
            float f[8] = {f0.x, f0.y, f0.z, f0.w, f1.x, f1.y, f1.z, f1.w};
            short8 ah, al;
            #pragma unroll
            for (int jj = 0; jj < 8; ++jj) {
                unsigned short hh, ll;
                cvt_hl(f[jj], hh, ll);
                ah[jj] = (short)hh; al[jj] = (short)ll;
            }
            const char* bp = smem + bb + ((j * 2 + g) * 2) * 1024 + lane * 16;
            short8 bh = *reinterpret_cast<const short8*>(bp);
            short8 bl = *reinterpret_cast<const short8*>(bp + 1024);
            acc = __builtin_amdgcn_mfma_f32_32x32x16_bf16(ah, bh, acc, 0, 0, 0);
            acc = __builtin_amdgcn_mfma_f32_32x32x16_bf16(al, bh, acc, 0, 0, 0);
            acc = __builtin_amdgcn_mfma_f32_32x32x16_bf16(ah, bl, acc, 0, 0, 0);
        }
        __builtin_amdgcn_sched_barrier(0);
        __builtin_amdgcn_s_barrier();       // write-protect buf for next stage
        __builtin_amdgcn_sched_barrier(0);
    }
    #undef STAGE

    // ---- logits -> LDS [64][68] f32 (C layout verified R5-R8) -------------
    float* lgs = reinterpret_cast<float*>(smem);
    __syncthreads();
    #pragma unroll
    for (int r = 0; r < 16; ++r) {          // col=lane&31, row=(r&3)+8*(r>>2)+4*l5
        const int lrow = wm * 32 + (r & 3) + 8 * (r >> 2) + 4 * l5;
        lgs[lrow * 68 + g * 32 + l31] = acc[r];
    }
    __syncthreads();

    // ---- row epilogue: 4 threads per row, 16 experts each (verified R5) ---
    const int erow = t >> 2, q = t & 3;
    float L[16];
    #pragma unroll
    for (int i = 0; i < 4; ++i) {
        float4 v = *reinterpret_cast<const float4*>(lgs + erow * 68 + q * 16 + i * 4);
        L[4*i] = v.x; L[4*i+1] = v.y; L[4*i+2] = v.z; L[4*i+3] = v.w;
    }
    float v1 = -3.4e38f, v2 = -3.4e38f, v3 = -3.4e38f;
    int   e1 = 1 << 30,  e2 = 1 << 30,  e3 = 1 << 30;
    #pragma unroll
    for (int i = 0; i < 16; ++i) {
        float v = L[i]; int e = q * 16 + i;
        if      (gt_(v, e, v1, e1)) { v3=v2; e3=e2; v2=v1; e2=e1; v1=v; e1=e; }
        else if (gt_(v, e, v2, e2)) { v3=v2; e3=e2; v2=v; e2=e; }
        else if (gt_(v, e, v3, e3)) { v3=v; e3=e; }
    }
    #pragma unroll
    for (int m = 1; m <= 2; m <<= 1) {      // merge the row's 4 lanes
        float o1 = __shfl_xor(v1, m), o2 = __shfl_xor(v2, m), o3 = __shfl_xor(v3, m);
        int  oe1 = __shfl_xor(e1, m), oe2 = __shfl_xor(e2, m), oe3 = __shfl_xor(e3, m);
        float n1, n2, n3; int m1, m2, m3;
        if (gt_(v1, e1, o1, oe1)) {
            n1 = v1; m1 = e1;
            if (gt_(v2, e2, o1, oe1)) {
                n2 = v2; m2 = e2;
                if (gt_(v3, e3, o1, oe1)) { n3 = v3; m3 = e3; } else { n3 = o1; m3 = oe1; }
            } else {
                n2 = o1; m2 = oe1;
                if (gt_(v2, e2, o2, oe2)) { n3 = v2; m3 = e2; } else { n3 = o2; m3 = oe2; }
            }
        } else {
            n1 = o1; m1 = oe1;
            if (gt_(o2, oe2, v1, e1)) {
                n2 = o2; m2 = oe2;
                if (gt_(o3, oe3, v1, e1)) { n3 = o3; m3 = oe3; } else { n3 = v1; m3 = e1; }
            } else {
                n2 = v1; m2 = e1;
                if (gt_(o2, oe2, v2, e2)) { n3 = o2; m3 = oe2; } else { n3 = v2; m3 = e2; }
            }
        }
        v1 = n1; e1 = m1; v2 = n2; e2 = m2; v3 = n3; e3 = m3;
    }
    float pr[16], sl = 0.0f;
    #pragma unroll
    for (int i = 0; i < 16; ++i) { pr[i] = expf(L[i] - v1); sl += pr[i]; }
    float S = sl;
    S += __shfl_xor(S, 1); S += __shfl_xor(S, 2);
    const float invS = 1.0f / S;
    #pragma unroll
    for (int i = 0; i < 16; ++i) pr[i] *= invS;
    // per-expert partial sums across this wave's 16 rows
    #pragma unroll
    for (int m = 4; m <= 32; m <<= 1)
        #pragma unroll
        for (int i = 0; i < 16; ++i) pr[i] += __shfl_xor(pr[i], m);
    float* auxred = lgs + 64 * 68;          // 4 waves x 64 experts
    if (lane < 4) {
        #pragma unroll
        for (int i = 0; i < 16; ++i) auxred[wave * 64 + q * 16 + i] = pr[i];
    }
    if (q == 0) {
        const float p1 = invS;              // exp(v1-v1)*invS
        const float p2 = expf(v2 - v1) * invS;
        const float dn = p1 + p2 + EPSF;
        const int r = row0 + erow;
        out[2 * r]                 = p1 / dn;
        out[2 * r + 1]             = p2 / dn;
        out[2 * NROWS + 2 * r]     = (float)e1;
        out[2 * NROWS + 2 * r + 1] = (float)e2;
        if (cap > 0 && (v1 - v2 < TAU || v2 - v3 < TAU)) {
            int pos = atomicAdd(cnt, 1);
            if (pos < cap) list[pos] = r;
        }
    }
    __syncthreads();
    if (t < 64) {
        float s = auxred[t] + auxred[64 + t] + auxred[128 + t] + auxred[192 + t];
        atomicAdd(&shard[(blockIdx.x & (NSHARD - 1)) * 64 + t], s);
    }
}

// ---------------------------------------------------------------------------
// Finalize: block 0 sums 8 aux shards -> aux loss; blocks 1..64 repair
// flagged rows with exact fp32 logits.
// ---------------------------------------------------------------------------
__global__ __launch_bounds__(256) void finalize_kernel(
    const float* __restrict__ x, const float* __restrict__ gw,
    float* __restrict__ out, const float* __restrict__ shard,
    const int* __restrict__ cnt, const int* __restrict__ list, int cap)
{
    if (blockIdx.x == 0) {
        const int tt = threadIdx.x;
        if (tt < 64) {
            float m = 0.0f;
            #pragma unroll
            for (int s = 0; s < NSHARD; ++s) m += shard[s * 64 + tt];
            m *= (1.0f / (float)NROWS);
            float v = m * logf(m + EPSF);
            #pragma unroll
            for (int k = 1; k <= 32; k <<= 1) v += __shfl_xor(v, k);
            if (tt == 0) out[4 * NROWS] = v;
        }
        return;
    }
    __shared__ float lg[64];
    const int n = (cap > 0) ? min(*cnt, cap) : 0;
    const int tt = threadIdx.x, e = tt >> 2, part = tt & 3;
    for (int j = (int)blockIdx.x - 1; j < n; j += 64) {
        const int row = list[j];
        const float* xr = x  + (size_t)row * DDIM + part * 256;
        const float* wr = gw + (size_t)e   * DDIM + part * 256;
        float a = 0.0f;
        #pragma unroll 8
        for (int kk = 0; kk < 64; ++kk) {
            float4 xv = *reinterpret_cast<const float4*>(xr + kk * 4);
            float4 wv = *reinterpret_cast<const float4*>(wr + kk * 4);
            a += xv.x * wv.x + xv.y * wv.y + xv.z * wv.z + xv.w * wv.w;
        }
        a += __shfl_xor(a, 1); a += __shfl_xor(a, 2);
        if (part == 0) lg[e] = a;
        __syncthreads();
        if (tt < 4) {
            const int q = tt;
            float v1 = -3.4e38f, v2 = -3.4e38f; int e1 = 1 << 30, e2 = 1 << 30;
            float Lr[16];
            #pragma unroll
            for (int i = 0; i < 16; ++i) {
                float v = Lr[i] = lg[q * 16 + i]; int ee = q * 16 + i;
                if      (gt_(v, ee, v1, e1)) { v2 = v1; e2 = e1; v1 = v; e1 = ee; }
                else if (gt_(v, ee, v2, e2)) { v2 = v; e2 = ee; }
            }
            #pragma unroll
            for (int m = 1; m <= 2; m <<= 1) {
                float o1 = __shfl_xor(v1, m), o2 = __shfl_xor(v2, m);
                int  oe1 = __shfl_xor(e1, m), oe2 = __shfl_xor(e2, m);
                float n1, n2; int m1, m2;
                if (gt_(v1, e1, o1, oe1)) {
                    n1 = v1; m1 = e1;
                    if (gt_(v2, e2, o1, oe1)) { n2 = v2; m2 = e2; } else { n2 = o1; m2 = oe1; }
                } else {
                    n1 = o1; m1 = oe1;
                    if (gt_(o2, oe2, v1, e1)) { n2 = o2; m2 = oe2; } else { n2 = v1; m2 = e1; }
                }
                v1 = n1; e1 = m1; v2 = n2; e2 = m2;
            }
            float s = 0.0f;
            #pragma unroll
            for (int i = 0; i < 16; ++i) s += expf(Lr[i] - v1);
            s += __shfl_xor(s, 1); s += __shfl_xor(s, 2);
            if (q == 0) {
                const float invS = 1.0f / s;
                const float p1 = invS, p2 = expf(v2 - v1) * invS;
                const float dn = p1 + p2 + EPSF;
                out[2 * row]                 = p1 / dn;
                out[2 * row + 1]             = p2 / dn;
                out[2 * NROWS + 2 * row]     = (float)e1;
                out[2 * NROWS + 2 * row + 1] = (float)e2;
            }
        }
        __syncthreads();
    }
}

extern "C" void kernel_launch(void* const* d_in, const int* in_sizes, int n_in,
                              void* d_out, int out_size, void* d_ws, size_t ws_size,
                              hipStream_t stream)
{
    const float* x  = (const float*)d_in[0];
    const float* gw = (const float*)d_in[1];
    float* out      = (float*)d_out;

    // d_ws layout: [wp 256KB][shard 2KB][cnt 4B pad->256B][list ...]
    unsigned short* wp = (unsigned short*)d_ws;
    float* shard   = (float*)((char*)d_ws + 262144);
    int*   cnt     = (int*)((char*)d_ws + 264192);
    int*   list    = (int*)((char*)d_ws + 264448);
    int cap = 0;
    if (ws_size >= 264448 + 4096) {
        size_t avail = (ws_size - 264448) / sizeof(int);
        cap = (avail > CAPMAX) ? CAPMAX : (int)avail;
    }

    hipLaunchKernelGGL(wpack_kernel, dim3(64), dim3(256), 0, stream,
                       gw, wp, shard, cnt);
    hipLaunchKernelGGL(moe_main, dim3(NROWS / 64), dim3(256), 65536, stream,
                       x, wp, out, shard, cnt, list, cap);
    hipLaunchKernelGGL(finalize_kernel, dim3(65), dim3(256), 0, stream,
                       x, gw, out, shard, cnt, list, cap);
}

// Round 10
// 61.027 us; speedup vs baseline: 1.8524x; 1.0228x over previous
//
#include <hip/hip_runtime.h>
#include <hip/hip_bf16.h>
#include <math.h>

#define NROWS 32768
#define DDIM  1024
#define NEXP  64
#define TAU   2e-4f
#define EPSF  1e-9f
#define CAPMAX 8192
#define NSHARD 8
#define NCH   32                 // chunks of BK=32 fp32 k (2 kc each)

typedef __attribute__((ext_vector_type(8)))  short  short8;
typedef __attribute__((ext_vector_type(16))) float  f32x16;
typedef __attribute__((address_space(3))) unsigned int       lds_u32;
typedef __attribute__((address_space(1))) const unsigned int g_u32;

// stable greater-than: value desc, index asc on ties (matches lax.top_k)
__device__ __forceinline__ bool gt_(float a, int ea, float b, int eb)
{ return a > b || (a == b && ea < eb); }

// split f into bf16 hi (RTNE) + bf16 lo (RTNE of exact residual).
// Hardware cvt path (compiler fuses pairs into v_cvt_pk_bf16_f32).
__device__ __forceinline__ void cvt_hl(float f, short& h, short& l)
{
    __hip_bfloat16 hb = __float2bfloat16(f);
    float r = f - __bfloat162float(hb);
    __hip_bfloat16 lb = __float2bfloat16(r);
    h = *reinterpret_cast<short*>(&hb);
    l = *reinterpret_cast<short*>(&lb);
}

// ---------------------------------------------------------------------------
// Pack gate_w ONCE into per-lane MFMA B-fragment order, bf16 hi+lo
// (fragment lane-mapping HW-verified R5-R9). Block 0 zeroes aux shards + cnt.
// wp bytes: ((kc*2+g)*2+pr)*1024 + lane*16  (kc 0..63, g expert-half, pr hi/lo)
// ---------------------------------------------------------------------------
__global__ void wpack_kernel(const float* __restrict__ gw,
                             unsigned short* __restrict__ wp,
                             float* __restrict__ shard,
                             int* __restrict__ cnt)
{
    if (blockIdx.x == 0) {
        shard[threadIdx.x]       = 0.0f;
        shard[256 + threadIdx.x] = 0.0f;
        if (threadIdx.x == 0) *cnt = 0;
    }
    const int kc = blockIdx.x;              // 0..63
    const int t  = threadIdx.x;             // 256
    const int lane = t & 63, g = (t >> 6) & 1, pr = t >> 7;
    const int e = g * 32 + (lane & 31);
    const int k = kc * 16 + (lane >> 5) * 8;
    float4 f0 = *reinterpret_cast<const float4*>(gw + (size_t)e * DDIM + k);
    float4 f1 = *reinterpret_cast<const float4*>(gw + (size_t)e * DDIM + k + 4);
    float f[8] = {f0.x, f0.y, f0.z, f0.w, f1.x, f1.y, f1.z, f1.w};
    short8 o;
    #pragma unroll
    for (int j = 0; j < 8; ++j) {
        short hh, ll;
        cvt_hl(f[j], hh, ll);
        o[j] = pr ? ll : hh;
    }
    *reinterpret_cast<short8*>(wp + ((size_t)((kc * 2 + g) * 2 + pr) * 64 + lane) * 8) = o;
}

// ---------------------------------------------------------------------------
// Main: 4-buffer pipelined MFMA GEMM, 3 chunks in flight (counted vmcnt).
// grid 512 x 256 thr; block = 64 rows x 64 experts; wave (wm,g) owns the
// 32x32 quadrant rows[wm*32..) x experts[g*32..), FULL K (no split-K).
// Chunk = BK=32 fp32 k (2 kc). Per iteration i:
//   STAGE(i+3): 4 global_load_lds(16B)/thread (x swizzled, B linear)
//   s_waitcnt vmcnt(12)  <- chunk i landed; i+1..i+3 stay IN FLIGHT
//   s_barrier; compute i (2 kc x {2 f4 ds_read + hw-cvt + 3 MFMA}); s_barrier
// x swizzle (rule 21, 128B rows): within-row byte ^= ((row&7)<<4); applied
// to BOTH global source (stage) and ds_read address.
// ---------------------------------------------------------------------------
__global__ __launch_bounds__(256, 2) void moe_main(
    const float* __restrict__ x, const unsigned short* __restrict__ wp,
    float* __restrict__ out, float* __restrict__ shard,
    int* __restrict__ cnt, int* __restrict__ list, int cap)
{
    extern __shared__ char smem[];          // 64 KB: x 4x8KB @0, B 4x8KB @32768

    const int t = threadIdx.x;
    const int wave = t >> 6, lane = t & 63;
    const int wm = wave & 1, g = wave >> 1;
    const int l31 = lane & 31, l5 = lane >> 5;
    const int row0 = blockIdx.x * 64;
    const int arow = wm * 32 + l31;         // this lane's x row within tile
    const int xr   = (arow & 7) << 4;       // read-side swizzle

    f32x16 acc;
    #pragma unroll
    for (int r = 0; r < 16; ++r) acc[r] = 0.0f;

    // staging map (swizzle precomputed per thread, 2 slots)
    int srow[2], scol[2];
    #pragma unroll
    for (int q = 0; q < 2; ++q) {
        int d = q * 4096 + t * 16;
        srow[q] = d >> 7;
        scol[q] = (d & 127) ^ ((srow[q] & 7) << 4);
    }

    #define STAGE(c_) do {                                                       \
        const char* xs0_ = (const char*)x + (size_t)row0 * 4096 + (size_t)(c_) * 128; \
        const char* bs0_ = (const char*)wp + (size_t)(c_) * 8192;                \
        const int xb_ = ((c_) & 3) * 8192;                                       \
        const int bb_ = 32768 + ((c_) & 3) * 8192;                               \
        _Pragma("unroll")                                                        \
        for (int q_ = 0; q_ < 2; ++q_) {                                         \
            int d_ = q_ * 4096 + t * 16;                                         \
            const char* xsrc_ = xs0_ + (size_t)srow[q_] * 4096 + scol[q_];       \
            __builtin_amdgcn_global_load_lds((g_u32*)xsrc_,                      \
                (lds_u32*)(smem + xb_ + d_), 16, 0, 0);                          \
            __builtin_amdgcn_global_load_lds((g_u32*)(bs0_ + d_),                \
                (lds_u32*)(smem + bb_ + d_), 16, 0, 0);                          \
        }                                                                        \
    } while (0)

    // prologue: 3 chunks in flight
    STAGE(0); STAGE(1); STAGE(2);

    for (int i = 0; i < NCH; ++i) {
        if (i < NCH - 3) {
            STAGE(i + 3);
            __builtin_amdgcn_sched_barrier(0);
            asm volatile("s_waitcnt vmcnt(12)" ::: "memory");
        } else if (i == NCH - 3) {
            asm volatile("s_waitcnt vmcnt(8)" ::: "memory");
        } else if (i == NCH - 2) {
            asm volatile("s_waitcnt vmcnt(4)" ::: "memory");
        } else {
            asm volatile("s_waitcnt vmcnt(0)" ::: "memory");
        }
        __builtin_amdgcn_s_barrier();
        __builtin_amdgcn_sched_barrier(0);

        const int xb = (i & 3) * 8192;
        const int bb = 32768 + (i & 3) * 8192;
        #pragma unroll
        for (int kcl = 0; kcl < 2; ++kcl) {
            const int cb = kcl * 64 + l5 * 32;          // within-row byte base
            const char* xrow = smem + xb + arow * 128;
            float4 f0 = *reinterpret_cast<const float4*>(xrow + (cb ^ xr));
            float4 f1 = *reinterpret_cast<const float4*>(xrow + ((cb + 16) ^ xr));
            float f[8] = {f0.x, f0.y, f0.z, f0.w, f1.x, f1.y, f1.z, f1.w};
            short8 ah, al;
            #pragma unroll
            for (int jj = 0; jj < 8; ++jj) {
                short hh, ll;
                cvt_hl(f[jj], hh, ll);
                ah[jj] = hh; al[jj] = ll;
            }
            const char* bp = smem + bb + ((kcl * 2 + g) * 2) * 1024 + lane * 16;
            short8 bh = *reinterpret_cast<const short8*>(bp);
            short8 bl = *reinterpret_cast<const short8*>(bp + 1024);
            acc = __builtin_amdgcn_mfma_f32_32x32x16_bf16(ah, bh, acc, 0, 0, 0);
            acc = __builtin_amdgcn_mfma_f32_32x32x16_bf16(al, bh, acc, 0, 0, 0);
            acc = __builtin_amdgcn_mfma_f32_32x32x16_bf16(ah, bl, acc, 0, 0, 0);
        }
        __builtin_amdgcn_sched_barrier(0);
        __builtin_amdgcn_s_barrier();       // protect buf (i+1)&3 overwrite
        __builtin_amdgcn_sched_barrier(0);
    }
    #undef STAGE

    // ---- logits -> LDS [64][68] f32 (C layout verified R5-R9) -------------
    float* lgs = reinterpret_cast<float*>(smem);
    __syncthreads();
    #pragma unroll
    for (int r = 0; r < 16; ++r) {          // col=lane&31, row=(r&3)+8*(r>>2)+4*l5
        const int lrow = wm * 32 + (r & 3) + 8 * (r >> 2) + 4 * l5;
        lgs[lrow * 68 + g * 32 + l31] = acc[r];
    }
    __syncthreads();

    // ---- row epilogue: 4 threads per row, 16 experts each (verified R5+) --
    const int erow = t >> 2, q = t & 3;
    float L[16];
    #pragma unroll
    for (int i = 0; i < 4; ++i) {
        float4 v = *reinterpret_cast<const float4*>(lgs + erow * 68 + q * 16 + i * 4);
        L[4*i] = v.x; L[4*i+1] = v.y; L[4*i+2] = v.z; L[4*i+3] = v.w;
    }
    float v1 = -3.4e38f, v2 = -3.4e38f, v3 = -3.4e38f;
    int   e1 = 1 << 30,  e2 = 1 << 30,  e3 = 1 << 30;
    #pragma unroll
    for (int i = 0; i < 16; ++i) {
        float v = L[i]; int e = q * 16 + i;
        if      (gt_(v, e, v1, e1)) { v3=v2; e3=e2; v2=v1; e2=e1; v1=v; e1=e; }
        else if (gt_(v, e, v2, e2)) { v3=v2; e3=e2; v2=v; e2=e; }
        else if (gt_(v, e, v3, e3)) { v3=v; e3=e; }
    }
    #pragma unroll
    for (int m = 1; m <= 2; m <<= 1) {      // merge the row's 4 lanes
        float o1 = __shfl_xor(v1, m), o2 = __shfl_xor(v2, m), o3 = __shfl_xor(v3, m);
        int  oe1 = __shfl_xor(e1, m), oe2 = __shfl_xor(e2, m), oe3 = __shfl_xor(e3, m);
        float n1, n2, n3; int m1, m2, m3;
        if (gt_(v1, e1, o1, oe1)) {
            n1 = v1; m1 = e1;
            if (gt_(v2, e2, o1, oe1)) {
                n2 = v2; m2 = e2;
                if (gt_(v3, e3, o1, oe1)) { n3 = v3; m3 = e3; } else { n3 = o1; m3 = oe1; }
            } else {
                n2 = o1; m2 = oe1;
                if (gt_(v2, e2, o2, oe2)) { n3 = v2; m3 = e2; } else { n3 = o2; m3 = oe2; }
            }
        } else {
            n1 = o1; m1 = oe1;
            if (gt_(o2, oe2, v1, e1)) {
                n2 = o2; m2 = oe2;
                if (gt_(o3, oe3, v1, e1)) { n3 = o3; m3 = oe3; } else { n3 = v1; m3 = e1; }
            } else {
                n2 = v1; m2 = e1;
                if (gt_(o2, oe2, v2, e2)) { n3 = o2; m3 = oe2; } else { n3 = v2; m3 = e2; }
            }
        }
        v1 = n1; e1 = m1; v2 = n2; e2 = m2; v3 = n3; e3 = m3;
    }
    float pr[16], sl = 0.0f;
    #pragma unroll
    for (int i = 0; i < 16; ++i) { pr[i] = expf(L[i] - v1); sl += pr[i]; }
    float S = sl;
    S += __shfl_xor(S, 1); S += __shfl_xor(S, 2);
    const float invS = 1.0f / S;
    #pragma unroll
    for (int i = 0; i < 16; ++i) pr[i] *= invS;
    // per-expert partial sums across this wave's 16 rows
    #pragma unroll
    for (int m = 4; m <= 32; m <<= 1)
        #pragma unroll
        for (int i = 0; i < 16; ++i) pr[i] += __shfl_xor(pr[i], m);
    float* auxred = lgs + 64 * 68;          // 4 waves x 64 experts
    if (lane < 4) {
        #pragma unroll
        for (int i = 0; i < 16; ++i) auxred[wave * 64 + q * 16 + i] = pr[i];
    }
    if (q == 0) {
        const float p1 = invS;              // exp(v1-v1)*invS
        const float p2 = expf(v2 - v1) * invS;
        const float dn = p1 + p2 + EPSF;
        const int r = row0 + erow;
        out[2 * r]                 = p1 / dn;
        out[2 * r + 1]             = p2 / dn;
        out[2 * NROWS + 2 * r]     = (float)e1;
        out[2 * NROWS + 2 * r + 1] = (float)e2;
        if (cap > 0 && (v1 - v2 < TAU || v2 - v3 < TAU)) {
            int pos = atomicAdd(cnt, 1);
            if (pos < cap) list[pos] = r;
        }
    }
    __syncthreads();
    if (t < 64) {
        float s = auxred[t] + auxred[64 + t] + auxred[128 + t] + auxred[192 + t];
        atomicAdd(&shard[(blockIdx.x & (NSHARD - 1)) * 64 + t], s);
    }
}

// ---------------------------------------------------------------------------
// Finalize: block 0 sums 8 aux shards -> aux loss; blocks 1..64 repair
// flagged rows with exact fp32 logits.
// ---------------------------------------------------------------------------
__global__ __launch_bounds__(256) void finalize_kernel(
    const float* __restrict__ x, const float* __restrict__ gw,
    float* __restrict__ out, const float* __restrict__ shard,
    const int* __restrict__ cnt, const int* __restrict__ list, int cap)
{
    if (blockIdx.x == 0) {
        const int tt = threadIdx.x;
        if (tt < 64) {
            float m = 0.0f;
            #pragma unroll
            for (int s = 0; s < NSHARD; ++s) m += shard[s * 64 + tt];
            m *= (1.0f / (float)NROWS);
            float v = m * logf(m + EPSF);
            #pragma unroll
            for (int k = 1; k <= 32; k <<= 1) v += __shfl_xor(v, k);
            if (tt == 0) out[4 * NROWS] = v;
        }
        return;
    }
    __shared__ float lg[64];
    const int n = (cap > 0) ? min(*cnt, cap) : 0;
    const int tt = threadIdx.x, e = tt >> 2, part = tt & 3;
    for (int j = (int)blockIdx.x - 1; j < n; j += 64) {
        const int row = list[j];
        const float* xrp = x  + (size_t)row * DDIM + part * 256;
        const float* wrp = gw + (size_t)e   * DDIM + part * 256;
        float a = 0.0f;
        #pragma unroll 8
        for (int kk = 0; kk < 64; ++kk) {
            float4 xv = *reinterpret_cast<const float4*>(xrp + kk * 4);
            float4 wv = *reinterpret_cast<const float4*>(wrp + kk * 4);
            a += xv.x * wv.x + xv.y * wv.y + xv.z * wv.z + xv.w * wv.w;
        }
        a += __shfl_xor(a, 1); a += __shfl_xor(a, 2);
        if (part == 0) lg[e] = a;
        __syncthreads();
        if (tt < 4) {
            const int q = tt;
            float v1 = -3.4e38f, v2 = -3.4e38f; int e1 = 1 << 30, e2 = 1 << 30;
            float Lr[16];
            #pragma unroll
            for (int i = 0; i < 16; ++i) {
                float v = Lr[i] = lg[q * 16 + i]; int ee = q * 16 + i;
                if      (gt_(v, ee, v1, e1)) { v2 = v1; e2 = e1; v1 = v; e1 = ee; }
                else if (gt_(v, ee, v2, e2)) { v2 = v; e2 = ee; }
            }
            #pragma unroll
            for (int m = 1; m <= 2; m <<= 1) {
                float o1 = __shfl_xor(v1, m), o2 = __shfl_xor(v2, m);
                int  oe1 = __shfl_xor(e1, m), oe2 = __shfl_xor(e2, m);
                float n1, n2; int m1, m2;
                if (gt_(v1, e1, o1, oe1)) {
                    n1 = v1; m1 = e1;
                    if (gt_(v2, e2, o1, oe1)) { n2 = v2; m2 = e2; } else { n2 = o1; m2 = oe1; }
                } else {
                    n1 = o1; m1 = oe1;
                    if (gt_(o2, oe2, v1, e1)) { n2 = o2; m2 = oe2; } else { n2 = v1; m2 = e1; }
                }
                v1 = n1; e1 = m1; v2 = n2; e2 = m2;
            }
            float s = 0.0f;
            #pragma unroll
            for (int i = 0; i < 16; ++i) s += expf(Lr[i] - v1);
            s += __shfl_xor(s, 1); s += __shfl_xor(s, 2);
            if (q == 0) {
                const float invS = 1.0f / s;
                const float p1 = invS, p2 = expf(v2 - v1) * invS;
                const float dn = p1 + p2 + EPSF;
                out[2 * row]                 = p1 / dn;
                out[2 * row + 1]             = p2 / dn;
                out[2 * NROWS + 2 * row]     = (float)e1;
                out[2 * NROWS + 2 * row + 1] = (float)e2;
            }
        }
        __syncthreads();
    }
}

extern "C" void kernel_launch(void* const* d_in, const int* in_sizes, int n_in,
                              void* d_out, int out_size, void* d_ws, size_t ws_size,
                              hipStream_t stream)
{
    const float* x  = (const float*)d_in[0];
    const float* gw = (const float*)d_in[1];
    float* out      = (float*)d_out;

    // d_ws layout: [wp 256KB][shard 2KB][cnt 4B pad->256B][list ...]
    unsigned short* wp = (unsigned short*)d_ws;
    float* shard   = (float*)((char*)d_ws + 262144);
    int*   cnt     = (int*)((char*)d_ws + 264192);
    int*   list    = (int*)((char*)d_ws + 264448);
    int cap = 0;
    if (ws_size >= 264448 + 4096) {
        size_t avail = (ws_size - 264448) / sizeof(int);
        cap = (avail > CAPMAX) ? CAPMAX : (int)avail;
    }

    hipLaunchKernelGGL(wpack_kernel, dim3(64), dim3(256), 0, stream,
                       gw, wp, shard, cnt);
    hipLaunchKernelGGL(moe_main, dim3(NROWS / 64), dim3(256), 65536, stream,
                       x, wp, out, shard, cnt, list, cap);
    hipLaunchKernelGGL(finalize_kernel, dim3(65), dim3(256), 0, stream,
                       x, gw, out, shard, cnt, list, cap);
}